// Round 1
// baseline (527.346 us; speedup 1.0000x reference)
//
#include <hip/hip_runtime.h>
#include <math.h>

#define B_ 16
#define D_ 128
#define HH 48
#define WW 48
#define N_ 2304          // 48*48
#define SCALE_ 16.0f
#define INV_TEMP 14.285714285714286f
#define EPS_ 1e-8f

// ws layout (float units)
#define OFF_T    0                       // 16*9 = 144
#define OFF_ACC  144                     // [0]=total, [1]=count
#define OFF_FA   160                     // B*N*D normalized feats_a, (b,n,d) row-major
#define OFF_WBT  (OFF_FA + B_*N_*D_)     // B*D*N normalized warped_b, (b,d,n) row-major
#define OFF_MASK (OFF_WBT + B_*N_*D_)    // B*N valid mask

// ---------------- K1: per-batch 3x3 transform T = S_inv @ Hs_b @ M3 @ inv(Hs_a) @ S
__global__ void k_transform(const float* __restrict__ Hs_a,
                            const float* __restrict__ Hs_b,
                            const float* __restrict__ M,
                            float* __restrict__ ws) {
    int b = threadIdx.x;
    if (b == 0) { ws[OFF_ACC] = 0.f; ws[OFF_ACC + 1] = 0.f; }
    if (b >= B_) return;
    float A[9], Bm[9];
    for (int i = 0; i < 9; ++i) { A[i] = Hs_a[b * 9 + i]; Bm[i] = Hs_b[b * 9 + i]; }
    // inv(A) via adjugate
    float c00 = A[4] * A[8] - A[5] * A[7];
    float c01 = A[5] * A[6] - A[3] * A[8];
    float c02 = A[3] * A[7] - A[4] * A[6];
    float det = A[0] * c00 + A[1] * c01 + A[2] * c02;
    float id = 1.0f / det;
    float inv[9];
    inv[0] = c00 * id;
    inv[1] = (A[2] * A[7] - A[1] * A[8]) * id;
    inv[2] = (A[1] * A[5] - A[2] * A[4]) * id;
    inv[3] = c01 * id;
    inv[4] = (A[0] * A[8] - A[2] * A[6]) * id;
    inv[5] = (A[2] * A[3] - A[0] * A[5]) * id;
    inv[6] = c02 * id;
    inv[7] = (A[1] * A[6] - A[0] * A[7]) * id;
    inv[8] = (A[0] * A[4] - A[1] * A[3]) * id;
    float M3[9] = {M[0], M[1], M[2], M[3], M[4], M[5], 0.f, 0.f, 1.f};
    float P1[9], P2[9];
    for (int i = 0; i < 3; ++i)
        for (int j = 0; j < 3; ++j) {
            float s = 0.f;
            for (int k = 0; k < 3; ++k) s += Bm[i * 3 + k] * M3[k * 3 + j];
            P1[i * 3 + j] = s;
        }
    for (int i = 0; i < 3; ++i)
        for (int j = 0; j < 3; ++j) {
            float s = 0.f;
            for (int k = 0; k < 3; ++k) s += P1[i * 3 + k] * inv[k * 3 + j];
            P2[i * 3 + j] = s;
        }
    const float sc[3] = {SCALE_, SCALE_, 1.f};
    for (int i = 0; i < 3; ++i)
        for (int j = 0; j < 3; ++j)
            ws[OFF_T + b * 9 + i * 3 + j] = P2[i * 3 + j] * sc[j] / sc[i];
}

// ---------------- K2: grid + mask + bilinear warp + L2 normalize; write faN (b,n,d) and wbT (b,d,n)
__global__ __launch_bounds__(128) void k_prep(const float* __restrict__ fa,
                                              const float* __restrict__ fb,
                                              float* __restrict__ ws) {
    const int n = blockIdx.x, b = blockIdx.y, d = threadIdx.x;
    const float* T = ws + OFF_T + b * 9;
    const float gx = (float)(n % WW), gy = (float)(n / WW);
    const float X = T[0] * gx + T[1] * gy + T[2];
    const float Y = T[3] * gx + T[4] * gy + T[5];
    const float Zh = T[6] * gx + T[7] * gy + T[8];
    const float z = Zh + EPS_;
    const float xn = 2.f * (X / z) / (float)(WW - 1) - 1.f;
    const float yn = 2.f * (Y / z) / (float)(HH - 1) - 1.f;
    const float msk = (xn >= -1.f && xn <= 1.f && yn >= -1.f && yn <= 1.f) ? 1.f : 0.f;
    const float ix = (xn + 1.f) * 0.5f * (float)(WW - 1);
    const float iy = (yn + 1.f) * 0.5f * (float)(HH - 1);
    const float x0 = floorf(ix), y0 = floorf(iy);
    const float wx1 = ix - x0, wx0 = 1.f - wx1;
    const float wy1 = iy - y0, wy0 = 1.f - wy1;
    const float* fbbd = fb + (size_t)(b * D_ + d) * (HH * WW);

    auto corner = [&](float xi, float yi) -> float {
        bool v = (xi >= 0.f) && (xi <= (float)(WW - 1)) && (yi >= 0.f) && (yi <= (float)(HH - 1));
        int xc = (int)fminf(fmaxf(xi, 0.f), (float)(WW - 1));
        int yc = (int)fminf(fmaxf(yi, 0.f), (float)(HH - 1));
        float val = fbbd[yc * WW + xc];
        return v ? val : 0.f;
    };
    float wbv = corner(x0, y0) * wx0 * wy0
              + corner(x0 + 1.f, y0) * wx1 * wy0
              + corner(x0, y0 + 1.f) * wx0 * wy1
              + corner(x0 + 1.f, y0 + 1.f) * wx1 * wy1;
    float fav = fa[(size_t)(b * D_ + d) * (HH * WW) + n];

    // block-wide sum of squares (128 threads = 2 waves)
    float sfa = fav * fav, swb = wbv * wbv;
    for (int off = 32; off >= 1; off >>= 1) {
        sfa += __shfl_xor(sfa, off);
        swb += __shfl_xor(swb, off);
    }
    __shared__ float red[4];
    if ((threadIdx.x & 63) == 0) {
        red[(threadIdx.x >> 6) * 2] = sfa;
        red[(threadIdx.x >> 6) * 2 + 1] = swb;
    }
    __syncthreads();
    sfa = red[0] + red[2];
    swb = red[1] + red[3];
    const float rfa = 1.f / fmaxf(sqrtf(sfa), 1e-12f);
    const float rwb = 1.f / fmaxf(sqrtf(swb), 1e-12f);
    ws[OFF_FA + (size_t)(b * N_ + n) * D_ + d] = fav * rfa;
    ws[OFF_WBT + (size_t)(b * D_ + d) * N_ + n] = wbv * rwb;
    if (d == 0) ws[OFF_MASK + b * N_ + n] = msk;
}

// ---------------- K3: fused logits + fixed-shift logsumexp + masked loss accumulation
#define TM 64
#define TN 64
#define AP 132  // padded LDS stride for A tile (2-way conflicts only = free)

__global__ __launch_bounds__(256) void k_loss(float* __restrict__ ws) {
    __shared__ float a_t[TM * AP];   // 33.8 KB
    __shared__ float b_t[D_ * TN];   // 32 KB, k-major [k][c]
    __shared__ float s_acc[2];
    const float* faN = ws + OFF_FA;
    const float* wbT = ws + OFF_WBT;
    const float* maskA = ws + OFF_MASK;
    const int bx = blockIdx.x;  // row tile index
    const int b = blockIdx.y;
    const int tid = threadIdx.x;
    const int tx = tid & 15, ty = tid >> 4;
    const int n0 = bx * TM;
    if (tid == 0) { s_acc[0] = 0.f; s_acc[1] = 0.f; }

    // load A tile once (coalesced global, conflict-free LDS write)
    {
        const int kk = (tid & 31) * 4;
        const int r0 = tid >> 5;
        const float* src = faN + (size_t)(b * N_ + n0) * D_;
        for (int p = 0; p < 8; ++p) {
            int r = r0 + p * 8;
            float4 v = *(const float4*)(src + (size_t)r * D_ + kk);
            *(float4*)(a_t + r * AP + kk) = v;
        }
    }

    float Zr[4] = {0.f, 0.f, 0.f, 0.f};
    float dg[4] = {0.f, 0.f, 0.f, 0.f};

    for (int jt = 0; jt < N_ / TN; ++jt) {
        __syncthreads();
        // load B tile: b_t[k*TN + c] from wbT (b,d,n) — coalesced along n
        {
            const int c4 = (tid & 15) * 4;
            const int k0 = tid >> 4;
            const float* src = wbT + (size_t)b * D_ * N_ + jt * TN;
            for (int p = 0; p < 8; ++p) {
                int k = k0 + p * 16;
                float4 v = *(const float4*)(src + (size_t)k * N_ + c4);
                *(float4*)(b_t + k * TN + c4) = v;
            }
        }
        __syncthreads();

        float acc[4][4] = {};
        const float* ap = a_t + ty * 4 * AP;
        const float* bp = b_t + tx * 4;
        for (int k4 = 0; k4 < D_ / 4; ++k4) {
            float Af[4][4], Bf[4][4];
            for (int i = 0; i < 4; ++i) {
                float4 t = *(const float4*)(ap + i * AP + k4 * 4);
                Af[i][0] = t.x; Af[i][1] = t.y; Af[i][2] = t.z; Af[i][3] = t.w;
            }
            for (int e = 0; e < 4; ++e) {
                float4 t = *(const float4*)(bp + (k4 * 4 + e) * TN);
                Bf[e][0] = t.x; Bf[e][1] = t.y; Bf[e][2] = t.z; Bf[e][3] = t.w;
            }
            for (int e = 0; e < 4; ++e)
                for (int i = 0; i < 4; ++i)
                    for (int j = 0; j < 4; ++j)
                        acc[i][j] += Af[i][e] * Bf[e][j];
        }

        const bool diagTile = (jt == bx);
        for (int i = 0; i < 4; ++i) {
            float rowsum = 0.f;
            for (int j = 0; j < 4; ++j) {
                float s = acc[i][j] * INV_TEMP;
                rowsum += __expf(s - INV_TEMP);
                if (diagTile && tx == ty && i == j) dg[i] = s;
            }
            Zr[i] += rowsum;
        }
    }

    // reduce Z across the 16 tx lanes (bits 0..3 of lane id)
    for (int i = 0; i < 4; ++i)
        for (int off = 1; off < 16; off <<= 1)
            Zr[i] += __shfl_xor(Zr[i], off);

    if (tx == ty) {
        float t = 0.f, c = 0.f;
        for (int i = 0; i < 4; ++i) {
            int r = ty * 4 + i;
            float m = maskA[b * N_ + n0 + r];
            float loss = logf(Zr[i]) + INV_TEMP - dg[i];
            t += loss * m;
            c += m;
        }
        atomicAdd(&s_acc[0], t);
        atomicAdd(&s_acc[1], c);
    }
    __syncthreads();
    if (tid == 0) {
        atomicAdd(ws + OFF_ACC, s_acc[0]);
        atomicAdd(ws + OFF_ACC + 1, s_acc[1]);
    }
}

// ---------------- K4: finalize
__global__ void k_final(const float* __restrict__ ws, float* __restrict__ out) {
    float t = ws[OFF_ACC], c = ws[OFF_ACC + 1];
    out[0] = (c > 0.f) ? t / fmaxf(c, 1.f) : 0.f;
}

extern "C" void kernel_launch(void* const* d_in, const int* in_sizes, int n_in,
                              void* d_out, int out_size, void* d_ws, size_t ws_size,
                              hipStream_t stream) {
    const float* fa = (const float*)d_in[0];
    const float* fb = (const float*)d_in[1];
    const float* Ha = (const float*)d_in[2];
    const float* Hb = (const float*)d_in[3];
    const float* M = (const float*)d_in[4];
    float* ws = (float*)d_ws;
    float* out = (float*)d_out;

    hipLaunchKernelGGL(k_transform, dim3(1), dim3(64), 0, stream, Ha, Hb, M, ws);
    hipLaunchKernelGGL(k_prep, dim3(N_, B_), dim3(128), 0, stream, fa, fb, ws);
    hipLaunchKernelGGL(k_loss, dim3(N_ / TM, B_), dim3(256), 0, stream, ws);
    hipLaunchKernelGGL(k_final, dim3(1), dim3(1), 0, stream, ws, out);
}

// Round 2
// 150.811 us; speedup vs baseline: 3.4967x; 3.4967x over previous
//
#include <hip/hip_runtime.h>
#include <math.h>

#define B_ 16
#define D_ 128
#define HH 48
#define WW 48
#define N_ 2304
#define SCALE_ 16.0f
#define INV_TEMP 14.285714285714286f
#define EPS_ 1e-8f
#define KP 136   // padded bf16 LDS row stride (272B: 16B-aligned, 4-bank row skew)

typedef __attribute__((ext_vector_type(8))) short bf16x8;
typedef __attribute__((ext_vector_type(16))) float f32x16;

__device__ __forceinline__ short f2bf(float f) {
    union { float f; unsigned u; } v; v.f = f;
    unsigned r = v.u + 0x7FFFu + ((v.u >> 16) & 1u);
    return (short)(r >> 16);
}

// ---------------- K2: transform + grid + mask + bilinear warp + L2 normalize -> bf16 (b,n,d)
__global__ __launch_bounds__(256) void k_prep(const float* __restrict__ fa,
                                              const float* __restrict__ fb,
                                              const float* __restrict__ Ha,
                                              const float* __restrict__ Hb,
                                              const float* __restrict__ Mab,
                                              float* __restrict__ maskA,
                                              short* __restrict__ faN,
                                              short* __restrict__ wbN) {
    __shared__ float bufA[64][132];
    __shared__ float bufW[64][132];
    __shared__ float part[4][2][64];
    __shared__ float rn[2][64];
    const int b = blockIdx.y;
    const int n0 = blockIdx.x * 64;
    const int tid = threadIdx.x;
    const int nl = tid & 63, dg = tid >> 6;
    const int n = n0 + nl;

    // per-batch transform T = S_inv @ Hb @ M3 @ inv(Ha) @ S  (computed redundantly per thread)
    float T[9];
    {
        const float* A = Ha + b * 9;
        const float* Bm = Hb + b * 9;
        float c00 = A[4] * A[8] - A[5] * A[7];
        float c01 = A[5] * A[6] - A[3] * A[8];
        float c02 = A[3] * A[7] - A[4] * A[6];
        float id = 1.f / (A[0] * c00 + A[1] * c01 + A[2] * c02);
        float inv[9] = { c00 * id, (A[2] * A[7] - A[1] * A[8]) * id, (A[1] * A[5] - A[2] * A[4]) * id,
                         c01 * id, (A[0] * A[8] - A[2] * A[6]) * id, (A[2] * A[3] - A[0] * A[5]) * id,
                         c02 * id, (A[1] * A[6] - A[0] * A[7]) * id, (A[0] * A[4] - A[1] * A[3]) * id };
        float M3[9] = {Mab[0], Mab[1], Mab[2], Mab[3], Mab[4], Mab[5], 0.f, 0.f, 1.f};
        float P1[9], P2[9];
        for (int i = 0; i < 3; ++i)
            for (int j = 0; j < 3; ++j) {
                float s = 0.f;
                for (int k = 0; k < 3; ++k) s += Bm[i * 3 + k] * M3[k * 3 + j];
                P1[i * 3 + j] = s;
            }
        for (int i = 0; i < 3; ++i)
            for (int j = 0; j < 3; ++j) {
                float s = 0.f;
                for (int k = 0; k < 3; ++k) s += P1[i * 3 + k] * inv[k * 3 + j];
                P2[i * 3 + j] = s;
            }
        const float sc[3] = {SCALE_, SCALE_, 1.f};
        for (int i = 0; i < 3; ++i)
            for (int j = 0; j < 3; ++j) T[i * 3 + j] = P2[i * 3 + j] * sc[j] / sc[i];
    }

    const float gx = (float)(n % WW), gy = (float)(n / WW);
    const float X = T[0] * gx + T[1] * gy + T[2];
    const float Y = T[3] * gx + T[4] * gy + T[5];
    const float z = T[6] * gx + T[7] * gy + T[8] + EPS_;
    const float xn = 2.f * (X / z) / (float)(WW - 1) - 1.f;
    const float yn = 2.f * (Y / z) / (float)(HH - 1) - 1.f;
    const float msk = (xn >= -1.f && xn <= 1.f && yn >= -1.f && yn <= 1.f) ? 1.f : 0.f;
    const float ix = (xn + 1.f) * 0.5f * (float)(WW - 1);
    const float iy = (yn + 1.f) * 0.5f * (float)(HH - 1);
    const float x0f = floorf(ix), y0f = floorf(iy);
    const float wx1 = ix - x0f, wx0 = 1.f - wx1;
    const float wy1 = iy - y0f, wy0 = 1.f - wy1;
    int offc[4]; float wgt[4];
    {
        float xs[2] = {x0f, x0f + 1.f}, ys[2] = {y0f, y0f + 1.f};
        float wxs[2] = {wx0, wx1}, wys[2] = {wy0, wy1};
        for (int cy = 0; cy < 2; ++cy)
            for (int cx = 0; cx < 2; ++cx) {
                float xi = xs[cx], yi = ys[cy];
                bool v = xi >= 0.f && xi <= (float)(WW - 1) && yi >= 0.f && yi <= (float)(HH - 1);
                int xc = (int)fminf(fmaxf(xi, 0.f), (float)(WW - 1));
                int yc = (int)fminf(fmaxf(yi, 0.f), (float)(HH - 1));
                offc[cy * 2 + cx] = yc * WW + xc;
                wgt[cy * 2 + cx] = v ? wxs[cx] * wys[cy] : 0.f;
            }
    }
    const float* fab = fa + (size_t)b * D_ * N_;
    const float* fbb = fb + (size_t)b * D_ * N_;
    float sA = 0.f, sW = 0.f;
    for (int dd = 0; dd < 32; ++dd) {
        int d = dg * 32 + dd;
        const float* p = fbb + (size_t)d * N_;
        float w = wgt[0] * p[offc[0]] + wgt[1] * p[offc[1]] + wgt[2] * p[offc[2]] + wgt[3] * p[offc[3]];
        float a = fab[(size_t)d * N_ + n];     // coalesced: lane=pixel, fixed d
        bufA[nl][d] = a;
        bufW[nl][d] = w;
        sA += a * a;
        sW += w * w;
    }
    part[dg][0][nl] = sA;
    part[dg][1][nl] = sW;
    __syncthreads();
    if (tid < 64) {
        float ta = part[0][0][tid] + part[1][0][tid] + part[2][0][tid] + part[3][0][tid];
        float tw = part[0][1][tid] + part[1][1][tid] + part[2][1][tid] + part[3][1][tid];
        rn[0][tid] = 1.f / fmaxf(sqrtf(ta), 1e-12f);
        rn[1][tid] = 1.f / fmaxf(sqrtf(tw), 1e-12f);
        maskA[b * N_ + n] = msk;   // tid<64 -> dg==0 -> n = n0+tid: this thread's own msk
    }
    __syncthreads();
    const int c = tid & 15;
    const int r0 = tid >> 4;
    for (int pp = 0; pp < 4; ++pp) {
        int r = pp * 16 + r0;
        float sa = rn[0][r], sw = rn[1][r];
        float4 a0 = *(float4*)&bufA[r][c * 8];
        float4 a1 = *(float4*)&bufA[r][c * 8 + 4];
        float4 w0 = *(float4*)&bufW[r][c * 8];
        float4 w1 = *(float4*)&bufW[r][c * 8 + 4];
        bf16x8 oa, ow;
        oa[0] = f2bf(a0.x * sa); oa[1] = f2bf(a0.y * sa); oa[2] = f2bf(a0.z * sa); oa[3] = f2bf(a0.w * sa);
        oa[4] = f2bf(a1.x * sa); oa[5] = f2bf(a1.y * sa); oa[6] = f2bf(a1.z * sa); oa[7] = f2bf(a1.w * sa);
        ow[0] = f2bf(w0.x * sw); ow[1] = f2bf(w0.y * sw); ow[2] = f2bf(w0.z * sw); ow[3] = f2bf(w0.w * sw);
        ow[4] = f2bf(w1.x * sw); ow[5] = f2bf(w1.y * sw); ow[6] = f2bf(w1.z * sw); ow[7] = f2bf(w1.w * sw);
        *(bf16x8*)(faN + (size_t)(b * N_ + n0 + r) * D_ + c * 8) = oa;   // 16B coalesced store
        *(bf16x8*)(wbN + (size_t)(b * N_ + n0 + r) * D_ + c * 8) = ow;
    }
}

// ---------------- K3: bf16 MFMA logits + fixed-shift logsumexp + masked loss
__global__ __launch_bounds__(256) void k_loss(const float* __restrict__ maskA,
                                              const short* __restrict__ faN,
                                              const short* __restrict__ wbN,
                                              float* __restrict__ acc) {
    __shared__ short a_t[64 * KP];
    __shared__ short b_t[64 * KP];
    __shared__ float s_Z[64];
    __shared__ float s_dg[64];
    const int bx = blockIdx.x, b = blockIdx.y;
    const int tid = threadIdx.x;
    const int n0 = bx * 64;
    const int c = tid & 15, r0 = tid >> 4;

    // stage A tile (64 rows x 128 k, bf16), padded stride
    for (int p = 0; p < 4; ++p) {
        int r = p * 16 + r0;
        bf16x8 v = *(const bf16x8*)(faN + (size_t)(b * N_ + n0 + r) * D_ + c * 8);
        *(bf16x8*)(a_t + r * KP + c * 8) = v;
    }
    if (tid < 64) { s_Z[tid] = 0.f; s_dg[tid] = 0.f; }
    __syncthreads();

    const int lane = tid & 63;
    const int wv = tid >> 6;
    const int rq = wv >> 1, cq = wv & 1;   // 2x2 wave quadrants of 32x32
    const int l31 = lane & 31, h = lane >> 5;

    // A fragments for this wave's 32 rows, all K=128 (held in registers across jt loop)
    bf16x8 afr[8];
    {
        const short* ap = a_t + (rq * 32 + l31) * KP + h * 8;
        for (int ks = 0; ks < 8; ++ks) afr[ks] = *(const bf16x8*)(ap + ks * 16);
    }
    float Z[16];
    for (int i = 0; i < 16; ++i) Z[i] = 0.f;

    for (int jt = 0; jt < N_ / 64; ++jt) {
        __syncthreads();
        for (int p = 0; p < 4; ++p) {
            int r = p * 16 + r0;
            bf16x8 v = *(const bf16x8*)(wbN + (size_t)(b * N_ + jt * 64 + r) * D_ + c * 8);
            *(bf16x8*)(b_t + r * KP + c * 8) = v;
        }
        __syncthreads();

        const short* bp = b_t + (cq * 32 + l31) * KP + h * 8;
        f32x16 C;
        for (int i = 0; i < 16; ++i) C[i] = 0.f;
        for (int ks = 0; ks < 8; ++ks) {
            bf16x8 bfr = *(const bf16x8*)(bp + ks * 16);
            C = __builtin_amdgcn_mfma_f32_32x32x16_bf16(afr[ks], bfr, C, 0, 0, 0);
        }
        // epilogue: fixed-shift exp accumulate (logit <= INV_TEMP always)
        for (int i = 0; i < 16; ++i)
            Z[i] += __expf(INV_TEMP * C[i] - INV_TEMP);

        if (jt == bx) {   // diagonal tile: capture diag logits
            int gcol_l = cq * 32 + l31;
            for (int i = 0; i < 16; ++i) {
                int rl = rq * 32 + (i & 3) + 8 * (i >> 2) + 4 * h;  // C/D row mapping (m74/m101)
                if (gcol_l == rl) s_dg[rl] = INV_TEMP * C[i];
            }
        }
    }
    // reduce Z over the 32 column lanes (xor of low 5 bits stays within half)
    for (int i = 0; i < 16; ++i) {
        float zz = Z[i];
        zz += __shfl_xor(zz, 1);
        zz += __shfl_xor(zz, 2);
        zz += __shfl_xor(zz, 4);
        zz += __shfl_xor(zz, 8);
        zz += __shfl_xor(zz, 16);
        Z[i] = zz;
    }
    if (l31 == 0) {
        for (int i = 0; i < 16; ++i) {
            int rl = rq * 32 + (i & 3) + 8 * (i >> 2) + 4 * h;
            atomicAdd(&s_Z[rl], Z[i]);   // two col-quadrant waves contribute per row
        }
    }
    __syncthreads();
    if (tid < 64) {
        float m = maskA[b * N_ + n0 + tid];
        float lossv = (logf(s_Z[tid]) + INV_TEMP - s_dg[tid]) * m;
        float cm = m;
        for (int off = 1; off < 64; off <<= 1) {
            lossv += __shfl_xor(lossv, off);
            cm += __shfl_xor(cm, off);
        }
        if (tid == 0) {
            atomicAdd(&acc[0], lossv);
            atomicAdd(&acc[1], cm);
        }
    }
}

// ---------------- K4: finalize
__global__ void k_final(const float* __restrict__ acc, float* __restrict__ out) {
    float t = acc[0], c = acc[1];
    out[0] = (c > 0.f) ? t / fmaxf(c, 1.f) : 0.f;
}

extern "C" void kernel_launch(void* const* d_in, const int* in_sizes, int n_in,
                              void* d_out, int out_size, void* d_ws, size_t ws_size,
                              hipStream_t stream) {
    const float* fa = (const float*)d_in[0];
    const float* fb = (const float*)d_in[1];
    const float* Ha = (const float*)d_in[2];
    const float* Hb = (const float*)d_in[3];
    const float* M = (const float*)d_in[4];
    float* out = (float*)d_out;

    float* wsf = (float*)d_ws;
    float* accp = wsf;                                   // [0]=loss sum, [1]=mask count
    float* maskA = wsf + 4;                              // B*N floats
    short* faN = (short*)(wsf + 4 + B_ * N_);            // B*N*D bf16, (b,n,d)
    short* wbN = faN + (size_t)B_ * N_ * D_;             // B*N*D bf16, (b,n,d)

    hipMemsetAsync(accp, 0, 2 * sizeof(float), stream);
    hipLaunchKernelGGL(k_prep, dim3(N_ / 64, B_), dim3(256), 0, stream,
                       fa, fb, Ha, Hb, M, maskA, faN, wbN);
    hipLaunchKernelGGL(k_loss, dim3(N_ / 64, B_), dim3(256), 0, stream,
                       maskA, faN, wbN, accp);
    hipLaunchKernelGGL(k_final, dim3(1), dim3(1), 0, stream, accp, out);
}